// Round 8
// baseline (233.051 us; speedup 1.0000x reference)
//
#include <hip/hip_runtime.h>
#include <hip/hip_bf16.h>
#include <stdint.h>

// Problem constants
constexpr int B_ = 8, N_ = 1024, DIM_ = 512, H_ = 8, D_ = 64;
constexpr int BH_ = B_ * H_;   // 64
constexpr int M_  = B_ * N_;   // 8192 rows
constexpr float SCALE_ = 0.04419417382415922f;    // 512^-0.5  (DIM, not D!)
constexpr float LOG2E_ = 1.44269504088896f;
constexpr float QSL2E_ = SCALE_ * LOG2E_;         // folded into W2 q-columns

typedef __bf16 bf16x8 __attribute__((ext_vector_type(8)));
typedef float  f32x4  __attribute__((ext_vector_type(4)));
typedef unsigned short u16;
typedef u16 u16x8 __attribute__((ext_vector_type(8)));
typedef u16 u16x4 __attribute__((ext_vector_type(4)));

// native convert -> compiler emits v_cvt_pk_bf16_f32 for pairs (RNE)
static __device__ __forceinline__ u16 f2bf(float f) {
  return __builtin_bit_cast(u16, (__bf16)f);
}
static __device__ __forceinline__ bf16x8 ld8(const u16* p) {
  return __builtin_bit_cast(bf16x8, *reinterpret_cast<const u16x8*>(p));
}
static __device__ __forceinline__ bf16x8 ld8b(const char* p) {
  return __builtin_bit_cast(bf16x8, *reinterpret_cast<const u16x8*>(p));
}
static __device__ __forceinline__ f32x4 mfma16(bf16x8 a, bf16x8 b, f32x4 c) {
  return __builtin_amdgcn_mfma_f32_16x16x32_bf16(a, b, c, 0, 0, 0);
}
// async global->LDS, 16B per lane; lds dest = wave-uniform base + lane*16
static __device__ __forceinline__ void gload_lds16(const u16* g, void* l) {
  __builtin_amdgcn_global_load_lds(
      (const __attribute__((address_space(1))) void*)g,
      (__attribute__((address_space(3))) void*)l, 16, 0, 0);
}

// ---------- fused pre-pass: x cast + mask scale + 3 weight transposes ----------
// block ranges (256 thr): [0,4096) xb | [4096,5120) mask | [5120,8192) W1t
// [8192,11264) W2t | [11264,12288) W3t
__global__ void k_prep(const float* __restrict__ x, const float* __restrict__ mask,
                       const float* __restrict__ W1, const float* __restrict__ W2,
                       const float* __restrict__ W3,
                       u16* __restrict__ xb, float* __restrict__ mk,
                       u16* __restrict__ W1t, u16* __restrict__ W2t, u16* __restrict__ W3t)
{
  const int b = blockIdx.x, t = threadIdx.x;
  if (b < 4096) {                      // x -> bf16, 1 float4/thread
    int idx = b * 256 + t;
    float4 v = reinterpret_cast<const float4*>(x)[idx];
    u16x4 o; o[0] = f2bf(v.x); o[1] = f2bf(v.y); o[2] = f2bf(v.z); o[3] = f2bf(v.w);
    reinterpret_cast<u16x4*>(xb)[idx] = o;
  } else if (b < 5120) {               // mask * -log2e
    int idx = (b - 4096) * 256 + t;
    float4 v = reinterpret_cast<const float4*>(mask)[idx];
    v.x *= -LOG2E_; v.y *= -LOG2E_; v.z *= -LOG2E_; v.w *= -LOG2E_;
    reinterpret_cast<float4*>(mk)[idx] = v;
  } else if (b < 8192) {               // W1 [512][1536] -> W1t [1536][512]
    int idx = (b - 5120) * 256 + t;
    int c = idx >> 9, k = idx & 511;
    W1t[idx] = f2bf(W1[k * 1536 + c]);
  } else if (b < 11264) {              // W2 -> W2t, q-cols scaled
    int idx = (b - 8192) * 256 + t;
    int c = idx >> 9, k = idx & 511;
    float v = W2[k * 1536 + c];
    if (c < 512) v *= QSL2E_;
    W2t[idx] = f2bf(v);
  } else {                             // W3 [512][512] -> W3t
    int idx = (b - 11264) * 256 + t;
    int c = idx >> 9, k = idx & 511;
    W3t[idx] = f2bf(W3[k * 512 + c]);
  }
}

// ---------- GEMM (m97 structure): 128x128 tile, BK=32, LDS double-buffered ----------
// MODE 0: scatter epilogue -> q,k [BH][N][D] bf16, v -> vt [BH][D][N] bf16 (packed u16x4).
// MODE 1: f32 out. SQ: scale bias of q-part (cols<512) by QSL2E_. XCD-aware swizzle.
template<int NC, int MODE, bool SQ>
__global__ __launch_bounds__(256) void k_gemm(
    const u16* __restrict__ A, const u16* __restrict__ Wt, const float* __restrict__ bias,
    u16* __restrict__ qo, u16* __restrict__ ko, u16* __restrict__ vto, float* __restrict__ fo)
{
  __shared__ __attribute__((aligned(16))) u16 As[2][128 * 32];
  __shared__ __attribute__((aligned(16))) u16 Bs[2][128 * 32];
  const int wv = threadIdx.x >> 6, ln = threadIdx.x & 63;
  const int lr = ln & 15, lg = ln >> 4;
  const int wr = wv >> 1, wc = wv & 1;
  const int nwg = gridDim.x * gridDim.y;
  const int lin = blockIdx.y * gridDim.x + blockIdx.x;
  const int swz = (lin & 7) * (nwg >> 3) + (lin >> 3);
  const int r0 = (swz & 63) * 128;          // gridDim.x == 64 always
  const int c0 = (swz >> 6) * 128;

  auto stage = [&](int bufi, int kk) {
#pragma unroll
    for (int q = 0; q < 2; ++q) {
      int L = (wv * 2 + q) * 1024 + ln * 16;
      int row = L >> 6;
      int col = ((L & 63) ^ (((row >> 1) & 3) << 4)) >> 1;
      gload_lds16(A  + (size_t)(r0 + row) * 512 + kk + col, (char*)As[bufi] + (wv * 2 + q) * 1024);
      gload_lds16(Wt + (size_t)(c0 + row) * 512 + kk + col, (char*)Bs[bufi] + (wv * 2 + q) * 1024);
    }
  };
  auto swzld = [&](const u16* tile, int row, int colb) -> bf16x8 {
    int byte = (row << 6) + (colb ^ (((row >> 1) & 3) << 4));
    return __builtin_bit_cast(bf16x8, *reinterpret_cast<const u16x8*>((const char*)tile + byte));
  };

  f32x4 acc[4][4] = {};
  stage(0, 0);
  int buf = 0;
  for (int kk = 0; kk < 512; kk += 32) {
    __syncthreads();
    if (kk + 32 < 512) stage(buf ^ 1, kk + 32);
    bf16x8 af[4], bfb[4];
#pragma unroll
    for (int m = 0; m < 4; ++m) af[m]  = swzld(As[buf], wr * 64 + m * 16 + lr, lg * 16);
#pragma unroll
    for (int n = 0; n < 4; ++n) bfb[n] = swzld(Bs[buf], wc * 64 + n * 16 + lr, lg * 16);
#pragma unroll
    for (int m = 0; m < 4; ++m)
#pragma unroll
      for (int n = 0; n < 4; ++n)
        acc[m][n] = mfma16(af[m], bfb[n], acc[m][n]);
    buf ^= 1;
  }

#pragma unroll
  for (int m = 0; m < 4; ++m)
#pragma unroll
    for (int n = 0; n < 4; ++n) {
      const int gc  = c0 + wc * 64 + n * 16 + lr;
      const int gr0 = r0 + wr * 64 + m * 16 + lg * 4;
      const float bsc = (SQ && gc < 512) ? QSL2E_ : 1.f;
      const float bv = bias[gc] * bsc;
      if (MODE == 0) {
        const int part = gc >> 9, cc = gc & 511;
        const int hh = cc >> 6, dd = cc & 63;
        const int bb = gr0 >> 10, nn = gr0 & 1023;
        const int bh = bb * H_ + hh;
        if (part == 2) {
          u16x4 w;
#pragma unroll
          for (int r = 0; r < 4; ++r) w[r] = f2bf(acc[m][n][r] + bv);
          *reinterpret_cast<u16x4*>(&vto[((size_t)(bh * D_ + dd)) * N_ + nn]) = w;
        } else {
          u16* dst = (part == 0 ? qo : ko) + ((size_t)(bh * N_ + nn)) * D_ + dd;
#pragma unroll
          for (int r = 0; r < 4; ++r) dst[(size_t)r * D_] = f2bf(acc[m][n][r] + bv);
        }
      } else {
#pragma unroll
        for (int r = 0; r < 4; ++r)
          fo[(size_t)(gr0 + r) * NC + gc] = acc[m][n][r] + bv;
      }
    }
}

// ---------- attention (swapped-QK^T, 4-wave blocks, 2-buffer syncthreads staging) ----------
// 4 waves x 16 q-rows = 64-row blocks, grid (16,64) -> 1024 blocks = 4/CU (37.9KB LDS),
// 16 waves/CU with 4-wave-wide barriers (halved lockstep domain vs round 7).
// Staging source pointers precomputed & incremented; all ds_read addresses are two
// per-lane bases (b0/b1) + compile-time immediates.
// Lane holds S^T: i = lr, j = js*16+lg*4+r. P via wave-private pbuf halves.
// STAGE 1: P = sigmoid(S*mask), mask pre-scaled by -log2e, prefetched.
// STAGE 2: P = exp2(S') unnormalized (fold in W2 q-cols); /sum at end.
template<int STAGE>
__global__ __launch_bounds__(256, 4) void k_attn(
    const u16* __restrict__ Q, const u16* __restrict__ K, const u16* __restrict__ Vt,
    const float* __restrict__ mask, u16* __restrict__ O)
{
  __shared__ __attribute__((aligned(16))) u16 Kb[2][64 * 64];
  __shared__ __attribute__((aligned(16))) u16 Vb[2][64 * 64];
  __shared__ __attribute__((aligned(16))) u16 pbuf[4][16][40];
  const int wv = threadIdx.x >> 6, ln = threadIdx.x & 63;
  const int lr = ln & 15, lg = ln >> 4;
  const int lin = blockIdx.y * gridDim.x + blockIdx.x;   // gridDim.x = 16
  const int swz = (lin & 7) * 128 + (lin >> 3);          // 128 blocks (8 bh) per XCD
  const int bh = swz >> 4;
  const int i0 = (swz & 15) * 64 + wv * 16;
  const size_t base = (size_t)bh * N_ * D_;

  // staging source pointers (per wave, 2 issues each for K and V), computed once
  const u16* kp[2]; const u16* vp[2];
#pragma unroll
  for (int q = 0; q < 2; ++q) {
    int L = (wv * 2 + q) * 1024 + ln * 16;               // byte offset in 8KB tile
    int row = L >> 7;
    int col = ((L & 127) ^ ((row & 7) << 4)) >> 1;       // inverse-swizzled source col
    kp[q] = K  + base + (size_t)row * 64 + col;          // + jt*64 per tile
    vp[q] = Vt + base + (size_t)row * 1024 + col;        // + jt per tile
  }
  auto stageKV = [&](int bufi, int jt2) {
#pragma unroll
    for (int q = 0; q < 2; ++q) {
      gload_lds16(kp[q] + (size_t)jt2 * 64, (char*)Kb[bufi] + (wv * 2 + q) * 1024);
      gload_lds16(vp[q] + jt2,              (char*)Vb[bufi] + (wv * 2 + q) * 1024);
    }
  };
  // hoisted swizzled LDS read bases: row*128 + (colb ^ ((row&7)<<4)), row=..+lr
  const int s_swz = (lr & 7) << 4;
  const int b0 = lr * 128 + ((lg * 16) ^ s_swz);
  const int b1 = lr * 128 + ((64 + lg * 16) ^ s_swz);

  // Q as the B-operand: lane holds query row i=lr, k-elems d = lg*8..+7
  bf16x8 aq0 = ld8(Q + base + (size_t)(i0 + lr) * D_ + lg * 8);
  bf16x8 aq1 = ld8(Q + base + (size_t)(i0 + lr) * D_ + 32 + lg * 8);

  f32x4 acco[4] = {};
  float ssum_ln = 0.f;

  float4 mk[4];
  const float* mrow = mask + (size_t)(i0 + lr) * N_;
  auto loadmask = [&](int jt2) {
#pragma unroll
    for (int js = 0; js < 4; ++js)
      mk[js] = *reinterpret_cast<const float4*>(&mrow[jt2 + js * 16 + lg * 4]);
  };
  if (STAGE == 1) loadmask(0);

  stageKV(0, 0);
  int buf = 0;
  for (int jt = 0; jt < N_; jt += 64) {
    __syncthreads();                       // buf ready (vmcnt drained); prev reads done
    if (jt + 64 < N_) stageKV(buf ^ 1, jt + 64);
    const char* Kt  = (const char*)Kb[buf];
    const char* Vtl = (const char*)Vb[buf];

    // S^T tiles: A = K rows j, B = Q rows i
    f32x4 s[4];
    __builtin_amdgcn_s_setprio(1);
#pragma unroll
    for (int js = 0; js < 4; ++js) {
      bf16x8 bk0 = ld8b(Kt + b0 + js * 2048);
      bf16x8 bk1 = ld8b(Kt + b1 + js * 2048);
      f32x4 z = {};
      z = mfma16(bk0, aq0, z);
      z = mfma16(bk1, aq1, z);
      s[js] = z;
    }
    __builtin_amdgcn_s_setprio(0);

    // P in two 32-col halves through wave-private pbuf
    float ps = 0.f;
#pragma unroll
    for (int h = 0; h < 2; ++h) {
#pragma unroll
      for (int js2 = 0; js2 < 2; ++js2) {
        const int js = h * 2 + js2;
        u16x4 w;
        if (STAGE == 1) {
#pragma unroll
          for (int r = 0; r < 4; ++r) {
            float mkr = (r == 0) ? mk[js].x : (r == 1) ? mk[js].y : (r == 2) ? mk[js].z : mk[js].w;
            float e = exp2f(s[js][r] * mkr);               // exp(-x*mask')
            w[r] = f2bf(__builtin_amdgcn_rcpf(1.f + e));   // sigmoid
          }
        } else {
#pragma unroll
          for (int r = 0; r < 4; ++r) {
            float p = exp2f(s[js][r]);                     // unnormalized
            ps += p;
            w[r] = f2bf(p);
          }
        }
        *reinterpret_cast<u16x4*>(&pbuf[wv][lr][js2 * 16 + lg * 4]) = w;
      }
      bf16x8 ap = ld8(&pbuf[wv][lr][lg * 8]);
      const int bh_base = (h == 0) ? b0 : b1;
      __builtin_amdgcn_s_setprio(1);
#pragma unroll
      for (int db = 0; db < 4; ++db) {
        bf16x8 bv = ld8b(Vtl + bh_base + db * 2048);
        acco[db] = mfma16(ap, bv, acco[db]);
      }
      __builtin_amdgcn_s_setprio(0);
    }
    if (STAGE == 2) ssum_ln += ps;
    if (STAGE == 1 && jt + 64 < N_) loadmask(jt + 64);  // prefetch next tile's mask
    buf ^= 1;
  }

  float inv[4];
  if (STAGE == 2) {
    float st = ssum_ln;
    st += __shfl_xor(st, 16);
    st += __shfl_xor(st, 32);    // total denom for query i=lr (uniform over lg)
#pragma unroll
    for (int r = 0; r < 4; ++r)
      inv[r] = __builtin_amdgcn_rcpf(__shfl(st, lg * 4 + r));
  }

  // epilogue: transpose O through pbuf in two halves -> 16B coalesced stores
  const int bb = bh >> 3, hh = bh & 7;
  u16* orow = O + (size_t)(bb * N_ + i0 + lr) * DIM_ + hh * D_;
#pragma unroll
  for (int h = 0; h < 2; ++h) {
#pragma unroll
    for (int db = 0; db < 2; ++db)
#pragma unroll
      for (int r = 0; r < 4; ++r) {
        float v = acco[h * 2 + db][r];
        if (STAGE == 2) v *= inv[r];
        pbuf[wv][lg * 4 + r][db * 16 + lr] = f2bf(v);
      }
    bf16x8 ov = ld8(&pbuf[wv][lr][lg * 8]);   // same-wave LDS, in-order pipe
    *reinterpret_cast<u16x8*>(orow + h * 32 + lg * 8) = __builtin_bit_cast(u16x8, ov);
  }
}

extern "C" void kernel_launch(void* const* d_in, const int* in_sizes, int n_in,
                              void* d_out, int out_size, void* d_ws, size_t ws_size,
                              hipStream_t stream)
{
  const float* x    = (const float*)d_in[0];
  const float* mask = (const float*)d_in[1];
  const float* W1   = (const float*)d_in[2];
  const float* b1   = (const float*)d_in[3];
  const float* W2   = (const float*)d_in[4];
  const float* b2   = (const float*)d_in[5];
  const float* W3   = (const float*)d_in[6];
  const float* b3   = (const float*)d_in[7];
  float* out = (float*)d_out;

  char* ws = (char*)d_ws;
  size_t off = 0;
  auto alloc = [&](size_t bytes) { char* p = ws + off; off += (bytes + 255) & ~255ULL; return p; };
  u16*   W1t = (u16*)alloc((size_t)1536 * 512 * 2);
  u16*   W2t = (u16*)alloc((size_t)1536 * 512 * 2);
  u16*   W3t = (u16*)alloc((size_t)512 * 512 * 2);
  u16*   xb  = (u16*)alloc((size_t)M_ * DIM_ * 2);      // x bf16; reused as out2
  u16*   q   = (u16*)alloc((size_t)BH_ * N_ * D_ * 2);
  u16*   k   = (u16*)alloc((size_t)BH_ * N_ * D_ * 2);
  u16*   vt  = (u16*)alloc((size_t)BH_ * N_ * D_ * 2);
  u16*   o1  = (u16*)alloc((size_t)M_ * DIM_ * 2);
  float* mk  = (float*)alloc((size_t)N_ * N_ * 4);      // mask * (-log2e)
  u16*   o2  = xb;

  k_prep<<<12288, 256, 0, stream>>>(x, mask, W1, W2, W3, xb, mk, W1t, W2t, W3t);

  dim3 g1(M_ / 128, 1536 / 128);
  k_gemm<1536, 0, false><<<g1, 256, 0, stream>>>(xb, W1t, b1, q, k, vt, nullptr);

  dim3 ga(16, BH_);
  k_attn<1><<<ga, 256, 0, stream>>>(q, k, vt, mk, o1);

  k_gemm<1536, 0, true><<<g1, 256, 0, stream>>>(o1, W2t, b2, q, k, vt, nullptr);

  k_attn<2><<<ga, 256, 0, stream>>>(q, k, vt, mk, o2);

  dim3 g3(M_ / 128, 512 / 128);
  k_gemm<512, 1, false><<<g3, 256, 0, stream>>>(o2, W3t, b3, nullptr, nullptr, nullptr, out);
}

// Round 9
// 225.297 us; speedup vs baseline: 1.0344x; 1.0344x over previous
//
#include <hip/hip_runtime.h>
#include <hip/hip_bf16.h>
#include <stdint.h>

// Problem constants
constexpr int B_ = 8, N_ = 1024, DIM_ = 512, H_ = 8, D_ = 64;
constexpr int BH_ = B_ * H_;   // 64
constexpr int M_  = B_ * N_;   // 8192 rows
constexpr float SCALE_ = 0.04419417382415922f;    // 512^-0.5  (DIM, not D!)
constexpr float LOG2E_ = 1.44269504088896f;
constexpr float QSL2E_ = SCALE_ * LOG2E_;         // folded into W2 q-columns

typedef __bf16 bf16x8 __attribute__((ext_vector_type(8)));
typedef float  f32x4  __attribute__((ext_vector_type(4)));
typedef unsigned short u16;
typedef u16 u16x8 __attribute__((ext_vector_type(8)));
typedef u16 u16x4 __attribute__((ext_vector_type(4)));

// native convert -> compiler emits v_cvt_pk_bf16_f32 for pairs (RNE)
static __device__ __forceinline__ u16 f2bf(float f) {
  return __builtin_bit_cast(u16, (__bf16)f);
}
static __device__ __forceinline__ bf16x8 ld8(const u16* p) {
  return __builtin_bit_cast(bf16x8, *reinterpret_cast<const u16x8*>(p));
}
static __device__ __forceinline__ f32x4 mfma16(bf16x8 a, bf16x8 b, f32x4 c) {
  return __builtin_amdgcn_mfma_f32_16x16x32_bf16(a, b, c, 0, 0, 0);
}
// async global->LDS, 16B per lane; lds dest = wave-uniform base + lane*16
static __device__ __forceinline__ void gload_lds16(const u16* g, void* l) {
  __builtin_amdgcn_global_load_lds(
      (const __attribute__((address_space(1))) void*)g,
      (__attribute__((address_space(3))) void*)l, 16, 0, 0);
}

// ---------- fused pre-pass ----------
// [0,4096) x->bf16 | [4096,5120) mask*-log2e | then LDS-tiled 64x64 W transposes:
// [5120,5312) W1 (8x24 tiles) | [5312,5504) W2 (q-cols scaled) | [5504,5568) W3 (8x8)
__global__ __launch_bounds__(256) void k_prep(
    const float* __restrict__ x, const float* __restrict__ mask,
    const float* __restrict__ W1, const float* __restrict__ W2,
    const float* __restrict__ W3,
    u16* __restrict__ xb, float* __restrict__ mk,
    u16* __restrict__ W1t, u16* __restrict__ W2t, u16* __restrict__ W3t)
{
  __shared__ float fl[64][65];
  const int b = blockIdx.x, t = threadIdx.x;
  if (b < 4096) {                      // x -> bf16, 1 float4/thread
    int idx = b * 256 + t;
    float4 v = reinterpret_cast<const float4*>(x)[idx];
    u16x4 o; o[0] = f2bf(v.x); o[1] = f2bf(v.y); o[2] = f2bf(v.z); o[3] = f2bf(v.w);
    reinterpret_cast<u16x4*>(xb)[idx] = o;
  } else if (b < 5120) {               // mask * -log2e
    int idx = (b - 4096) * 256 + t;
    float4 v = reinterpret_cast<const float4*>(mask)[idx];
    v.x *= -LOG2E_; v.y *= -LOG2E_; v.z *= -LOG2E_; v.w *= -LOG2E_;
    reinterpret_cast<float4*>(mk)[idx] = v;
  } else {                             // W[512][NC] -> Wt[NC][512], tiled transpose
    int tb = b - 5120;
    const float* Ws; u16* Wd; int NC, kt, ct; bool isW2 = false;
    if (tb < 192)      { Ws = W1; Wd = W1t; NC = 1536; kt = tb / 24; ct = tb % 24; }
    else if (tb < 384) { tb -= 192; Ws = W2; Wd = W2t; NC = 1536; kt = tb / 24; ct = tb % 24; isW2 = true; }
    else               { tb -= 384; Ws = W3; Wd = W3t; NC = 512;  kt = tb >> 3; ct = tb & 7; }
    const int tr = t >> 4, tc = t & 15;
#pragma unroll
    for (int i = 0; i < 4; ++i) {      // coalesced float4 reads, 64x64 tile
      int row = i * 16 + tr;
      float4 v = *reinterpret_cast<const float4*>(
          &Ws[(size_t)(kt * 64 + row) * NC + ct * 64 + tc * 4]);
      fl[row][tc * 4 + 0] = v.x; fl[row][tc * 4 + 1] = v.y;
      fl[row][tc * 4 + 2] = v.z; fl[row][tc * 4 + 3] = v.w;
    }
    __syncthreads();
#pragma unroll
    for (int i = 0; i < 4; ++i) {      // coalesced u16x4 transposed writes
      int wr = i * 16 + tr;
      int c = ct * 64 + wr;
      float sc = (isW2 && c < 512) ? QSL2E_ : 1.f;
      u16x4 w;
#pragma unroll
      for (int e = 0; e < 4; ++e) w[e] = f2bf(fl[tc * 4 + e][wr] * sc);
      *reinterpret_cast<u16x4*>(&Wd[(size_t)c * 512 + kt * 64 + tc * 4]) = w;
    }
  }
}

// ---------- GEMM (m97 structure): 128x128 tile, BK=32, LDS double-buffered ----------
// MODE 0: scatter epilogue -> q,k [BH][N][D] bf16, v -> vt [BH][D][N] bf16 (packed u16x4).
// MODE 1: f32 out. SQ: scale bias of q-part (cols<512) by QSL2E_. XCD-aware swizzle.
template<int NC, int MODE, bool SQ>
__global__ __launch_bounds__(256) void k_gemm(
    const u16* __restrict__ A, const u16* __restrict__ Wt, const float* __restrict__ bias,
    u16* __restrict__ qo, u16* __restrict__ ko, u16* __restrict__ vto, float* __restrict__ fo)
{
  __shared__ __attribute__((aligned(16))) u16 As[2][128 * 32];
  __shared__ __attribute__((aligned(16))) u16 Bs[2][128 * 32];
  const int wv = threadIdx.x >> 6, ln = threadIdx.x & 63;
  const int lr = ln & 15, lg = ln >> 4;
  const int wr = wv >> 1, wc = wv & 1;
  const int nwg = gridDim.x * gridDim.y;
  const int lin = blockIdx.y * gridDim.x + blockIdx.x;
  const int swz = (lin & 7) * (nwg >> 3) + (lin >> 3);
  const int r0 = (swz & 63) * 128;          // gridDim.x == 64 always
  const int c0 = (swz >> 6) * 128;

  auto stage = [&](int bufi, int kk) {
#pragma unroll
    for (int q = 0; q < 2; ++q) {
      int L = (wv * 2 + q) * 1024 + ln * 16;
      int row = L >> 6;
      int col = ((L & 63) ^ (((row >> 1) & 3) << 4)) >> 1;
      gload_lds16(A  + (size_t)(r0 + row) * 512 + kk + col, (char*)As[bufi] + (wv * 2 + q) * 1024);
      gload_lds16(Wt + (size_t)(c0 + row) * 512 + kk + col, (char*)Bs[bufi] + (wv * 2 + q) * 1024);
    }
  };
  auto swzld = [&](const u16* tile, int row, int colb) -> bf16x8 {
    int byte = (row << 6) + (colb ^ (((row >> 1) & 3) << 4));
    return __builtin_bit_cast(bf16x8, *reinterpret_cast<const u16x8*>((const char*)tile + byte));
  };

  f32x4 acc[4][4] = {};
  stage(0, 0);
  int buf = 0;
  for (int kk = 0; kk < 512; kk += 32) {
    __syncthreads();
    if (kk + 32 < 512) stage(buf ^ 1, kk + 32);
    bf16x8 af[4], bfb[4];
#pragma unroll
    for (int m = 0; m < 4; ++m) af[m]  = swzld(As[buf], wr * 64 + m * 16 + lr, lg * 16);
#pragma unroll
    for (int n = 0; n < 4; ++n) bfb[n] = swzld(Bs[buf], wc * 64 + n * 16 + lr, lg * 16);
#pragma unroll
    for (int m = 0; m < 4; ++m)
#pragma unroll
      for (int n = 0; n < 4; ++n)
        acc[m][n] = mfma16(af[m], bfb[n], acc[m][n]);
    buf ^= 1;
  }

#pragma unroll
  for (int m = 0; m < 4; ++m)
#pragma unroll
    for (int n = 0; n < 4; ++n) {
      const int gc  = c0 + wc * 64 + n * 16 + lr;
      const int gr0 = r0 + wr * 64 + m * 16 + lg * 4;
      const float bsc = (SQ && gc < 512) ? QSL2E_ : 1.f;
      const float bv = bias[gc] * bsc;
      if (MODE == 0) {
        const int part = gc >> 9, cc = gc & 511;
        const int hh = cc >> 6, dd = cc & 63;
        const int bb = gr0 >> 10, nn = gr0 & 1023;
        const int bh = bb * H_ + hh;
        if (part == 2) {
          u16x4 w;
#pragma unroll
          for (int r = 0; r < 4; ++r) w[r] = f2bf(acc[m][n][r] + bv);
          *reinterpret_cast<u16x4*>(&vto[((size_t)(bh * D_ + dd)) * N_ + nn]) = w;
        } else {
          u16* dst = (part == 0 ? qo : ko) + ((size_t)(bh * N_ + nn)) * D_ + dd;
#pragma unroll
          for (int r = 0; r < 4; ++r) dst[(size_t)r * D_] = f2bf(acc[m][n][r] + bv);
        }
      } else {
#pragma unroll
        for (int r = 0; r < 4; ++r)
          fo[(size_t)(gr0 + r) * NC + gc] = acc[m][n][r] + bv;
      }
    }
}

// ---------- attention (round-4 proven config: swapped-QK^T, 8 waves, 2-buffer sync) ----------
// 8 waves x 16 q-rows = 128-row blocks, grid (8, 64). K/V tiles LDS-staged, XOR-swizzled,
// double-buffered. Lane holds S^T: i = lr, j = js*16+lg*4+r. P via wave-private pbuf.
// STAGE 1: P = sigmoid(S*mask), mask pre-scaled by -log2e, prefetched.
// STAGE 2: P = exp2(S') unnormalized (SCALE*log2e folded into W2 q-cols); /sum at end.
template<int STAGE>
__global__ __launch_bounds__(512, 4) void k_attn(
    const u16* __restrict__ Q, const u16* __restrict__ K, const u16* __restrict__ Vt,
    const float* __restrict__ mask, u16* __restrict__ O)
{
  __shared__ __attribute__((aligned(16))) u16 Kb[2][64 * 64];
  __shared__ __attribute__((aligned(16))) u16 Vb[2][64 * 64];
  __shared__ __attribute__((aligned(16))) u16 pbuf[8][16][72];
  const int wv = threadIdx.x >> 6, ln = threadIdx.x & 63;
  const int lr = ln & 15, lg = ln >> 4;
  const int bh = blockIdx.y;
  const int i0 = blockIdx.x * 128 + wv * 16;
  const size_t base = (size_t)bh * N_ * D_;

  auto stageKV = [&](int bufi, int jt2) {
    int L = wv * 1024 + ln * 16;
    int row = L >> 7;
    int col = ((L & 127) ^ ((row & 7) << 4)) >> 1;
    gload_lds16(K  + base + (size_t)(jt2 + row) * 64 + col,  (char*)Kb[bufi] + wv * 1024);
    gload_lds16(Vt + base + (size_t)row * 1024 + jt2 + col,  (char*)Vb[bufi] + wv * 1024);
  };
  auto swzld = [&](const u16* tile, int row, int colb) -> bf16x8 {
    int byte = (row << 7) + (colb ^ ((row & 7) << 4));
    return __builtin_bit_cast(bf16x8, *reinterpret_cast<const u16x8*>((const char*)tile + byte));
  };

  // Q as the B-operand: lane holds query row i=lr, k-elems d = lg*8..+7
  bf16x8 aq0 = ld8(Q + base + (size_t)(i0 + lr) * D_ + lg * 8);
  bf16x8 aq1 = ld8(Q + base + (size_t)(i0 + lr) * D_ + 32 + lg * 8);

  f32x4 acco[4] = {};
  float ssum_ln = 0.f;    // per-lane partial softmax denom (query i = lr)

  float4 mk[4];
  const float* mrow = mask + (size_t)(i0 + lr) * N_;
  auto loadmask = [&](int jt2) {
#pragma unroll
    for (int js = 0; js < 4; ++js)
      mk[js] = *reinterpret_cast<const float4*>(&mrow[jt2 + js * 16 + lg * 4]);
  };
  if (STAGE == 1) loadmask(0);

  stageKV(0, 0);
  int buf = 0;
  for (int jt = 0; jt < N_; jt += 64) {
    __syncthreads();
    if (jt + 64 < N_) stageKV(buf ^ 1, jt + 64);

    // S^T tiles: A = K rows j, B = Q rows i
    f32x4 s[4];
    __builtin_amdgcn_s_setprio(1);
#pragma unroll
    for (int js = 0; js < 4; ++js) {
      int krow = js * 16 + lr;
      bf16x8 bk0 = swzld(Kb[buf], krow, lg * 16);
      bf16x8 bk1 = swzld(Kb[buf], krow, 64 + lg * 16);
      f32x4 z = {};
      z = mfma16(bk0, aq0, z);
      z = mfma16(bk1, aq1, z);
      s[js] = z;
    }
    __builtin_amdgcn_s_setprio(0);

    if (STAGE == 1) {
#pragma unroll
      for (int js = 0; js < 4; ++js) {
        u16x4 w;
#pragma unroll
        for (int r = 0; r < 4; ++r) {
          float mkr = (r == 0) ? mk[js].x : (r == 1) ? mk[js].y : (r == 2) ? mk[js].z : mk[js].w;
          float e = exp2f(s[js][r] * mkr);               // exp(-x*mask')
          w[r] = f2bf(__builtin_amdgcn_rcpf(1.f + e));   // sigmoid
        }
        *reinterpret_cast<u16x4*>(&pbuf[wv][lr][js * 16 + lg * 4]) = w;
      }
      if (jt + 64 < N_) loadmask(jt + 64);   // prefetch next tile's mask
    } else {
      float ps = 0.f;
#pragma unroll
      for (int js = 0; js < 4; ++js) {
        u16x4 w;
#pragma unroll
        for (int r = 0; r < 4; ++r) {
          float p = exp2f(s[js][r]);                     // unnormalized, logits bounded
          ps += p;
          w[r] = f2bf(p);
        }
        *reinterpret_cast<u16x4*>(&pbuf[wv][lr][js * 16 + lg * 4]) = w;
      }
      ssum_ln += ps;
    }

    // PV: P[16x64] @ V[64x64]
    bf16x8 ap0 = ld8(&pbuf[wv][lr][lg * 8]);
    bf16x8 ap1 = ld8(&pbuf[wv][lr][32 + lg * 8]);
    __builtin_amdgcn_s_setprio(1);
#pragma unroll
    for (int db = 0; db < 4; ++db) {
      bf16x8 bv0 = swzld(Vb[buf], db * 16 + lr, lg * 16);
      bf16x8 bv1 = swzld(Vb[buf], db * 16 + lr, 64 + lg * 16);
      acco[db] = mfma16(ap1, bv1, mfma16(ap0, bv0, acco[db]));
    }
    __builtin_amdgcn_s_setprio(0);
    buf ^= 1;
  }

  float inv[4];
  if (STAGE == 2) {
    float st = ssum_ln;
    st += __shfl_xor(st, 16);
    st += __shfl_xor(st, 32);    // total denom for query i=lr (uniform over lg)
#pragma unroll
    for (int r = 0; r < 4; ++r)
      inv[r] = __builtin_amdgcn_rcpf(__shfl(st, lg * 4 + r));
  }

  // epilogue: transpose O tile through pbuf -> 2x16B coalesced stores per lane
#pragma unroll
  for (int db = 0; db < 4; ++db)
#pragma unroll
    for (int r = 0; r < 4; ++r) {
      float v = acco[db][r];
      if (STAGE == 2) v *= inv[r];
      pbuf[wv][lg * 4 + r][db * 16 + lr] = f2bf(v);     // row i, col d
    }
  bf16x8 o0v = ld8(&pbuf[wv][lr][lg * 8]);              // same-wave LDS, compiler waits
  bf16x8 o1v = ld8(&pbuf[wv][lr][32 + lg * 8]);
  const int bb = bh >> 3, hh = bh & 7;
  u16* orow = O + (size_t)(bb * N_ + i0 + lr) * DIM_ + hh * D_;
  *reinterpret_cast<u16x8*>(orow + lg * 8)      = __builtin_bit_cast(u16x8, o0v);
  *reinterpret_cast<u16x8*>(orow + 32 + lg * 8) = __builtin_bit_cast(u16x8, o1v);
}

extern "C" void kernel_launch(void* const* d_in, const int* in_sizes, int n_in,
                              void* d_out, int out_size, void* d_ws, size_t ws_size,
                              hipStream_t stream)
{
  const float* x    = (const float*)d_in[0];
  const float* mask = (const float*)d_in[1];
  const float* W1   = (const float*)d_in[2];
  const float* b1   = (const float*)d_in[3];
  const float* W2   = (const float*)d_in[4];
  const float* b2   = (const float*)d_in[5];
  const float* W3   = (const float*)d_in[6];
  const float* b3   = (const float*)d_in[7];
  float* out = (float*)d_out;

  char* ws = (char*)d_ws;
  size_t off = 0;
  auto alloc = [&](size_t bytes) { char* p = ws + off; off += (bytes + 255) & ~255ULL; return p; };
  u16*   W1t = (u16*)alloc((size_t)1536 * 512 * 2);
  u16*   W2t = (u16*)alloc((size_t)1536 * 512 * 2);
  u16*   W3t = (u16*)alloc((size_t)512 * 512 * 2);
  u16*   xb  = (u16*)alloc((size_t)M_ * DIM_ * 2);      // x bf16; reused as out2
  u16*   q   = (u16*)alloc((size_t)BH_ * N_ * D_ * 2);
  u16*   k   = (u16*)alloc((size_t)BH_ * N_ * D_ * 2);
  u16*   vt  = (u16*)alloc((size_t)BH_ * N_ * D_ * 2);
  u16*   o1  = (u16*)alloc((size_t)M_ * DIM_ * 2);
  float* mk  = (float*)alloc((size_t)N_ * N_ * 4);      // mask * (-log2e)
  u16*   o2  = xb;

  k_prep<<<5568, 256, 0, stream>>>(x, mask, W1, W2, W3, xb, mk, W1t, W2t, W3t);

  dim3 g1(M_ / 128, 1536 / 128);
  k_gemm<1536, 0, false><<<g1, 256, 0, stream>>>(xb, W1t, b1, q, k, vt, nullptr);

  dim3 ga(N_ / 128, BH_);
  k_attn<1><<<ga, 512, 0, stream>>>(q, k, vt, mk, o1);

  k_gemm<1536, 0, true><<<g1, 256, 0, stream>>>(o1, W2t, b2, q, k, vt, nullptr);

  k_attn<2><<<ga, 512, 0, stream>>>(q, k, vt, mk, o2);

  dim3 g3(M_ / 128, 512 / 128);
  k_gemm<512, 1, false><<<g3, 256, 0, stream>>>(o2, W3t, b3, nullptr, nullptr, nullptr, out);
}

// Round 10
// 220.092 us; speedup vs baseline: 1.0589x; 1.0236x over previous
//
#include <hip/hip_runtime.h>
#include <hip/hip_bf16.h>
#include <stdint.h>

// Problem constants
constexpr int B_ = 8, N_ = 1024, DIM_ = 512, H_ = 8, D_ = 64;
constexpr int BH_ = B_ * H_;   // 64
constexpr int M_  = B_ * N_;   // 8192 rows
constexpr float SCALE_ = 0.04419417382415922f;    // 512^-0.5  (DIM, not D!)
constexpr float LOG2E_ = 1.44269504088896f;
constexpr float QSL2E_ = SCALE_ * LOG2E_;         // folded into W2 q-columns

typedef __bf16 bf16x8 __attribute__((ext_vector_type(8)));
typedef float  f32x4  __attribute__((ext_vector_type(4)));
typedef unsigned short u16;
typedef u16 u16x8 __attribute__((ext_vector_type(8)));
typedef u16 u16x4 __attribute__((ext_vector_type(4)));

// native convert -> compiler emits v_cvt_pk_bf16_f32 for pairs (RNE)
static __device__ __forceinline__ u16 f2bf(float f) {
  return __builtin_bit_cast(u16, (__bf16)f);
}
static __device__ __forceinline__ bf16x8 ld8(const u16* p) {
  return __builtin_bit_cast(bf16x8, *reinterpret_cast<const u16x8*>(p));
}
static __device__ __forceinline__ f32x4 mfma16(bf16x8 a, bf16x8 b, f32x4 c) {
  return __builtin_amdgcn_mfma_f32_16x16x32_bf16(a, b, c, 0, 0, 0);
}
// async global->LDS, 16B per lane; lds dest = wave-uniform base + lane*16
static __device__ __forceinline__ void gload_lds16(const u16* g, void* l) {
  __builtin_amdgcn_global_load_lds(
      (const __attribute__((address_space(1))) void*)g,
      (__attribute__((address_space(3))) void*)l, 16, 0, 0);
}

// ---------- fused pre-pass ----------
// [0,4096) x->bf16 | [4096,5120) mask*-log2e | then LDS-tiled 64x64 W transposes:
// [5120,5312) W1 (8x24 tiles) | [5312,5504) W2 (q-cols scaled) | [5504,5568) W3 (8x8)
__global__ __launch_bounds__(256) void k_prep(
    const float* __restrict__ x, const float* __restrict__ mask,
    const float* __restrict__ W1, const float* __restrict__ W2,
    const float* __restrict__ W3,
    u16* __restrict__ xb, float* __restrict__ mk,
    u16* __restrict__ W1t, u16* __restrict__ W2t, u16* __restrict__ W3t)
{
  __shared__ float fl[64][65];
  const int b = blockIdx.x, t = threadIdx.x;
  if (b < 4096) {                      // x -> bf16, 1 float4/thread
    int idx = b * 256 + t;
    float4 v = reinterpret_cast<const float4*>(x)[idx];
    u16x4 o; o[0] = f2bf(v.x); o[1] = f2bf(v.y); o[2] = f2bf(v.z); o[3] = f2bf(v.w);
    reinterpret_cast<u16x4*>(xb)[idx] = o;
  } else if (b < 5120) {               // mask * -log2e
    int idx = (b - 4096) * 256 + t;
    float4 v = reinterpret_cast<const float4*>(mask)[idx];
    v.x *= -LOG2E_; v.y *= -LOG2E_; v.z *= -LOG2E_; v.w *= -LOG2E_;
    reinterpret_cast<float4*>(mk)[idx] = v;
  } else {                             // W[512][NC] -> Wt[NC][512], tiled transpose
    int tb = b - 5120;
    const float* Ws; u16* Wd; int NC, kt, ct; bool isW2 = false;
    if (tb < 192)      { Ws = W1; Wd = W1t; NC = 1536; kt = tb / 24; ct = tb % 24; }
    else if (tb < 384) { tb -= 192; Ws = W2; Wd = W2t; NC = 1536; kt = tb / 24; ct = tb % 24; isW2 = true; }
    else               { tb -= 384; Ws = W3; Wd = W3t; NC = 512;  kt = tb >> 3; ct = tb & 7; }
    const int tr = t >> 4, tc = t & 15;
#pragma unroll
    for (int i = 0; i < 4; ++i) {      // coalesced float4 reads, 64x64 tile
      int row = i * 16 + tr;
      float4 v = *reinterpret_cast<const float4*>(
          &Ws[(size_t)(kt * 64 + row) * NC + ct * 64 + tc * 4]);
      fl[row][tc * 4 + 0] = v.x; fl[row][tc * 4 + 1] = v.y;
      fl[row][tc * 4 + 2] = v.z; fl[row][tc * 4 + 3] = v.w;
    }
    __syncthreads();
#pragma unroll
    for (int i = 0; i < 4; ++i) {      // coalesced u16x4 transposed writes
      int wr = i * 16 + tr;
      int c = ct * 64 + wr;
      float sc = (isW2 && c < 512) ? QSL2E_ : 1.f;
      u16x4 w;
#pragma unroll
      for (int e = 0; e < 4; ++e) w[e] = f2bf(fl[tc * 4 + e][wr] * sc);
      *reinterpret_cast<u16x4*>(&Wd[(size_t)c * 512 + kt * 64 + tc * 4]) = w;
    }
  }
}

// ---------- GEMM (m97 structure): 128x128 tile, BK=32, LDS double-buffered ----------
// MODE 0: scatter epilogue -> q,k [BH][N][D] bf16, v -> vt [BH][D][N] bf16 (packed u16x4).
// MODE 1: f32 out. SQ: scale bias of q-part (cols<512) by QSL2E_. XCD-aware swizzle.
template<int NC, int MODE, bool SQ>
__global__ __launch_bounds__(256) void k_gemm(
    const u16* __restrict__ A, const u16* __restrict__ Wt, const float* __restrict__ bias,
    u16* __restrict__ qo, u16* __restrict__ ko, u16* __restrict__ vto, float* __restrict__ fo)
{
  __shared__ __attribute__((aligned(16))) u16 As[2][128 * 32];
  __shared__ __attribute__((aligned(16))) u16 Bs[2][128 * 32];
  const int wv = threadIdx.x >> 6, ln = threadIdx.x & 63;
  const int lr = ln & 15, lg = ln >> 4;
  const int wr = wv >> 1, wc = wv & 1;
  const int nwg = gridDim.x * gridDim.y;
  const int lin = blockIdx.y * gridDim.x + blockIdx.x;
  const int swz = (lin & 7) * (nwg >> 3) + (lin >> 3);
  const int r0 = (swz & 63) * 128;          // gridDim.x == 64 always
  const int c0 = (swz >> 6) * 128;

  auto stage = [&](int bufi, int kk) {
#pragma unroll
    for (int q = 0; q < 2; ++q) {
      int L = (wv * 2 + q) * 1024 + ln * 16;
      int row = L >> 6;
      int col = ((L & 63) ^ (((row >> 1) & 3) << 4)) >> 1;
      gload_lds16(A  + (size_t)(r0 + row) * 512 + kk + col, (char*)As[bufi] + (wv * 2 + q) * 1024);
      gload_lds16(Wt + (size_t)(c0 + row) * 512 + kk + col, (char*)Bs[bufi] + (wv * 2 + q) * 1024);
    }
  };
  auto swzld = [&](const u16* tile, int row, int colb) -> bf16x8 {
    int byte = (row << 6) + (colb ^ (((row >> 1) & 3) << 4));
    return __builtin_bit_cast(bf16x8, *reinterpret_cast<const u16x8*>((const char*)tile + byte));
  };

  f32x4 acc[4][4] = {};
  stage(0, 0);
  int buf = 0;
  for (int kk = 0; kk < 512; kk += 32) {
    __syncthreads();
    if (kk + 32 < 512) stage(buf ^ 1, kk + 32);
    bf16x8 af[4], bfb[4];
#pragma unroll
    for (int m = 0; m < 4; ++m) af[m]  = swzld(As[buf], wr * 64 + m * 16 + lr, lg * 16);
#pragma unroll
    for (int n = 0; n < 4; ++n) bfb[n] = swzld(Bs[buf], wc * 64 + n * 16 + lr, lg * 16);
#pragma unroll
    for (int m = 0; m < 4; ++m)
#pragma unroll
      for (int n = 0; n < 4; ++n)
        acc[m][n] = mfma16(af[m], bfb[n], acc[m][n]);
    buf ^= 1;
  }

#pragma unroll
  for (int m = 0; m < 4; ++m)
#pragma unroll
    for (int n = 0; n < 4; ++n) {
      const int gc  = c0 + wc * 64 + n * 16 + lr;
      const int gr0 = r0 + wr * 64 + m * 16 + lg * 4;
      const float bsc = (SQ && gc < 512) ? QSL2E_ : 1.f;
      const float bv = bias[gc] * bsc;
      if (MODE == 0) {
        const int part = gc >> 9, cc = gc & 511;
        const int hh = cc >> 6, dd = cc & 63;
        const int bb = gr0 >> 10, nn = gr0 & 1023;
        const int bh = bb * H_ + hh;
        if (part == 2) {
          u16x4 w;
#pragma unroll
          for (int r = 0; r < 4; ++r) w[r] = f2bf(acc[m][n][r] + bv);
          *reinterpret_cast<u16x4*>(&vto[((size_t)(bh * D_ + dd)) * N_ + nn]) = w;
        } else {
          u16* dst = (part == 0 ? qo : ko) + ((size_t)(bh * N_ + nn)) * D_ + dd;
#pragma unroll
          for (int r = 0; r < 4; ++r) dst[(size_t)r * D_] = f2bf(acc[m][n][r] + bv);
        }
      } else {
#pragma unroll
        for (int r = 0; r < 4; ++r)
          fo[(size_t)(gr0 + r) * NC + gc] = acc[m][n][r] + bv;
      }
    }
}

// ---------- attention (round-4 structure + bh-contiguous XCD swizzle) ----------
// 8 waves x 16 q-rows = 128-row blocks, grid (8, 64). K/V tiles LDS-staged, XOR-swizzled,
// double-buffered. XCD x handles bh [8x,8x+8): K/V/q produced by same-XCD GEMM stay in
// its L2; mask (4MB) reused 8x per XCD.  Lane holds S^T: i = lr, j = js*16+lg*4+r.
// STAGE 1: P = sigmoid(S*mask), mask pre-scaled by -log2e, prefetched.
// STAGE 2: P = exp2(S') unnormalized (SCALE*log2e folded into W2 q-cols); /sum at end.
template<int STAGE>
__global__ __launch_bounds__(512, 4) void k_attn(
    const u16* __restrict__ Q, const u16* __restrict__ K, const u16* __restrict__ Vt,
    const float* __restrict__ mask, u16* __restrict__ O)
{
  __shared__ __attribute__((aligned(16))) u16 Kb[2][64 * 64];
  __shared__ __attribute__((aligned(16))) u16 Vb[2][64 * 64];
  __shared__ __attribute__((aligned(16))) u16 pbuf[8][16][72];
  const int wv = threadIdx.x >> 6, ln = threadIdx.x & 63;
  const int lr = ln & 15, lg = ln >> 4;
  const int lin = blockIdx.y * gridDim.x + blockIdx.x;   // gridDim.x = 8, 512 blocks
  const int swz = (lin & 7) * 64 + (lin >> 3);           // XCD x: swz [64x,64x+64) -> bh [8x,8x+8)
  const int bh = swz >> 3;
  const int i0 = (swz & 7) * 128 + wv * 16;
  const size_t base = (size_t)bh * N_ * D_;

  auto stageKV = [&](int bufi, int jt2) {
    int L = wv * 1024 + ln * 16;
    int row = L >> 7;
    int col = ((L & 127) ^ ((row & 7) << 4)) >> 1;
    gload_lds16(K  + base + (size_t)(jt2 + row) * 64 + col,  (char*)Kb[bufi] + wv * 1024);
    gload_lds16(Vt + base + (size_t)row * 1024 + jt2 + col,  (char*)Vb[bufi] + wv * 1024);
  };
  auto swzld = [&](const u16* tile, int row, int colb) -> bf16x8 {
    int byte = (row << 7) + (colb ^ ((row & 7) << 4));
    return __builtin_bit_cast(bf16x8, *reinterpret_cast<const u16x8*>((const char*)tile + byte));
  };

  // Q as the B-operand: lane holds query row i=lr, k-elems d = lg*8..+7
  bf16x8 aq0 = ld8(Q + base + (size_t)(i0 + lr) * D_ + lg * 8);
  bf16x8 aq1 = ld8(Q + base + (size_t)(i0 + lr) * D_ + 32 + lg * 8);

  f32x4 acco[4] = {};
  float ssum_ln = 0.f;    // per-lane partial softmax denom (query i = lr)

  float4 mk[4];
  const float* mrow = mask + (size_t)(i0 + lr) * N_;
  auto loadmask = [&](int jt2) {
#pragma unroll
    for (int js = 0; js < 4; ++js)
      mk[js] = *reinterpret_cast<const float4*>(&mrow[jt2 + js * 16 + lg * 4]);
  };
  if (STAGE == 1) loadmask(0);

  stageKV(0, 0);
  int buf = 0;
  for (int jt = 0; jt < N_; jt += 64) {
    __syncthreads();
    if (jt + 64 < N_) stageKV(buf ^ 1, jt + 64);

    // S^T tiles: A = K rows j, B = Q rows i
    f32x4 s[4];
    __builtin_amdgcn_s_setprio(1);
#pragma unroll
    for (int js = 0; js < 4; ++js) {
      int krow = js * 16 + lr;
      bf16x8 bk0 = swzld(Kb[buf], krow, lg * 16);
      bf16x8 bk1 = swzld(Kb[buf], krow, 64 + lg * 16);
      f32x4 z = {};
      z = mfma16(bk0, aq0, z);
      z = mfma16(bk1, aq1, z);
      s[js] = z;
    }
    __builtin_amdgcn_s_setprio(0);

    if (STAGE == 1) {
#pragma unroll
      for (int js = 0; js < 4; ++js) {
        u16x4 w;
#pragma unroll
        for (int r = 0; r < 4; ++r) {
          float mkr = (r == 0) ? mk[js].x : (r == 1) ? mk[js].y : (r == 2) ? mk[js].z : mk[js].w;
          float e = exp2f(s[js][r] * mkr);               // exp(-x*mask')
          w[r] = f2bf(__builtin_amdgcn_rcpf(1.f + e));   // sigmoid
        }
        *reinterpret_cast<u16x4*>(&pbuf[wv][lr][js * 16 + lg * 4]) = w;
      }
      if (jt + 64 < N_) loadmask(jt + 64);   // prefetch next tile's mask
    } else {
      float ps = 0.f;
#pragma unroll
      for (int js = 0; js < 4; ++js) {
        u16x4 w;
#pragma unroll
        for (int r = 0; r < 4; ++r) {
          float p = exp2f(s[js][r]);                     // unnormalized, logits bounded
          ps += p;
          w[r] = f2bf(p);
        }
        *reinterpret_cast<u16x4*>(&pbuf[wv][lr][js * 16 + lg * 4]) = w;
      }
      ssum_ln += ps;
    }

    // PV: P[16x64] @ V[64x64]
    bf16x8 ap0 = ld8(&pbuf[wv][lr][lg * 8]);
    bf16x8 ap1 = ld8(&pbuf[wv][lr][32 + lg * 8]);
    __builtin_amdgcn_s_setprio(1);
#pragma unroll
    for (int db = 0; db < 4; ++db) {
      bf16x8 bv0 = swzld(Vb[buf], db * 16 + lr, lg * 16);
      bf16x8 bv1 = swzld(Vb[buf], db * 16 + lr, 64 + lg * 16);
      acco[db] = mfma16(ap1, bv1, mfma16(ap0, bv0, acco[db]));
    }
    __builtin_amdgcn_s_setprio(0);
    buf ^= 1;
  }

  float inv[4];
  if (STAGE == 2) {
    float st = ssum_ln;
    st += __shfl_xor(st, 16);
    st += __shfl_xor(st, 32);    // total denom for query i=lr (uniform over lg)
#pragma unroll
    for (int r = 0; r < 4; ++r)
      inv[r] = __builtin_amdgcn_rcpf(__shfl(st, lg * 4 + r));
  }

  // epilogue: transpose O tile through pbuf -> 2x16B coalesced stores per lane
#pragma unroll
  for (int db = 0; db < 4; ++db)
#pragma unroll
    for (int r = 0; r < 4; ++r) {
      float v = acco[db][r];
      if (STAGE == 2) v *= inv[r];
      pbuf[wv][lg * 4 + r][db * 16 + lr] = f2bf(v);     // row i, col d
    }
  bf16x8 o0v = ld8(&pbuf[wv][lr][lg * 8]);              // same-wave LDS, compiler waits
  bf16x8 o1v = ld8(&pbuf[wv][lr][32 + lg * 8]);
  const int bb = bh >> 3, hh = bh & 7;
  u16* orow = O + (size_t)(bb * N_ + i0 + lr) * DIM_ + hh * D_;
  *reinterpret_cast<u16x8*>(orow + lg * 8)      = __builtin_bit_cast(u16x8, o0v);
  *reinterpret_cast<u16x8*>(orow + 32 + lg * 8) = __builtin_bit_cast(u16x8, o1v);
}

extern "C" void kernel_launch(void* const* d_in, const int* in_sizes, int n_in,
                              void* d_out, int out_size, void* d_ws, size_t ws_size,
                              hipStream_t stream)
{
  const float* x    = (const float*)d_in[0];
  const float* mask = (const float*)d_in[1];
  const float* W1   = (const float*)d_in[2];
  const float* b1   = (const float*)d_in[3];
  const float* W2   = (const float*)d_in[4];
  const float* b2   = (const float*)d_in[5];
  const float* W3   = (const float*)d_in[6];
  const float* b3   = (const float*)d_in[7];
  float* out = (float*)d_out;

  char* ws = (char*)d_ws;
  size_t off = 0;
  auto alloc = [&](size_t bytes) { char* p = ws + off; off += (bytes + 255) & ~255ULL; return p; };
  u16*   W1t = (u16*)alloc((size_t)1536 * 512 * 2);
  u16*   W2t = (u16*)alloc((size_t)1536 * 512 * 2);
  u16*   W3t = (u16*)alloc((size_t)512 * 512 * 2);
  u16*   xb  = (u16*)alloc((size_t)M_ * DIM_ * 2);      // x bf16; reused as out2
  u16*   q   = (u16*)alloc((size_t)BH_ * N_ * D_ * 2);
  u16*   k   = (u16*)alloc((size_t)BH_ * N_ * D_ * 2);
  u16*   vt  = (u16*)alloc((size_t)BH_ * N_ * D_ * 2);
  u16*   o1  = (u16*)alloc((size_t)M_ * DIM_ * 2);
  float* mk  = (float*)alloc((size_t)N_ * N_ * 4);      // mask * (-log2e)
  u16*   o2  = xb;

  k_prep<<<5568, 256, 0, stream>>>(x, mask, W1, W2, W3, xb, mk, W1t, W2t, W3t);

  dim3 g1(M_ / 128, 1536 / 128);
  k_gemm<1536, 0, false><<<g1, 256, 0, stream>>>(xb, W1t, b1, q, k, vt, nullptr);

  dim3 ga(N_ / 128, BH_);
  k_attn<1><<<ga, 512, 0, stream>>>(q, k, vt, mk, o1);

  k_gemm<1536, 0, true><<<g1, 256, 0, stream>>>(o1, W2t, b2, q, k, vt, nullptr);

  k_attn<2><<<ga, 512, 0, stream>>>(q, k, vt, mk, o2);

  dim3 g3(M_ / 128, 512 / 128);
  k_gemm<512, 1, false><<<g3, 256, 0, stream>>>(o2, W3t, b3, nullptr, nullptr, nullptr, out);
}